// Round 7
// baseline (466.131 us; speedup 1.0000x reference)
//
#include <hip/hip_runtime.h>
#include <stdint.h>

// CTC forward NLL, B=32, T=2000, V=1024, S=128, L=2S+1=257.
// Two-phase:
// Phase 1 (16000 blocks x 256): stage a row-pair (8 KB) in LDS, gather
//   2x129 entries, exp+clamp, store pair-packed labels (16 B/lane/pair).
//   Block 0 zeroes out[0] (no separate memset dispatch).
// Phase 2 (32 blocks x 1 wave): DP with an LDS-DMA ring:
//   14-slot x 3 KB LDS ring filled by __builtin_amdgcn_global_load_lds
//   (3 x 1 KB per 6-row chunk; ~39 KB in flight, vmcnt(36) pacing),
//   consumed via double-banked ds_read_b128 x3 + lgkmcnt(3) waits
//   (always-safe: waited bank's reads are older than all ops issued this
//   section). Zero in-flight-load register pressure (r5/r6 failure mode:
//   >100 VGPRs of async load destinations -> allocator copies/spills read
//   stale data). Single wave: no barriers, no implicit compiler drains.
//   All waits volatile asm with dependent regs tied "+v"; stok data-chains
//   DMA addresses after the most recent wait (r3-proven discipline).

#define LOG2E_F 1.4426950408889634f
#define LN2_F   0.6931471805599453f

constexpr int CB = 32;       // batch
constexpr int CT = 2000;     // time
constexpr int CV = 1024;     // vocab
constexpr int CS = 128;      // max target len
constexpr float PMIN = 9.5367431640625e-07f;  // 2^-20

typedef float f4 __attribute__((ext_vector_type(4)));
typedef __attribute__((address_space(3))) float lds_float;
typedef __attribute__((address_space(3))) void lds_void;
typedef __attribute__((address_space(1))) const void gconst_void;

__device__ __forceinline__ float pexp(float x) {
    return fmaxf(exp2f(x * LOG2E_F), PMIN);
}

// ---------------- phase 1: row-pair gather ----------------
__global__ __launch_bounds__(256) void ctc_gather2(const float* __restrict__ lp,
                                                   const int* __restrict__ targets,
                                                   float* __restrict__ lab2,
                                                   float* __restrict__ pbuf,
                                                   float* __restrict__ out) {
    __shared__ float rows[2048];             // 8 KB: rows t0, t0+1
    const int bt2 = blockIdx.x;              // b*1000 + t2
    const int tid = threadIdx.x;
    const int b   = bt2 / 1000;
    const int t0  = 2 * (bt2 - b * 1000);
    const f4* src = (const f4*)(lp + ((size_t)b * CT + t0) * CV);
    ((f4*)rows)[tid]       = src[tid];
    ((f4*)rows)[tid + 256] = src[tid + 256];
    __syncthreads();
    if (tid < 64) {
        const int tg0 = targets[b * CS + 2 * tid];
        const int tg1 = targets[b * CS + 2 * tid + 1];
        f4 v;
        v.x = pexp(rows[tg0]);           // row t0,   state 2*tid
        v.y = pexp(rows[tg1]);           // row t0,   state 2*tid+1
        v.z = pexp(rows[1024 + tg0]);    // row t0+1, state 2*tid
        v.w = pexp(rows[1024 + tg1]);    // row t0+1, state 2*tid+1
        ((f4*)lab2)[(size_t)bt2 * 64 + tid] = v;
    } else if (tid == 64) {
        pbuf[(size_t)b * CT + t0] = pexp(rows[0]);
    } else if (tid == 65) {
        pbuf[(size_t)b * CT + t0 + 1] = pexp(rows[1024]);
    } else if (tid == 66 && bt2 == 0) {
        out[0] = 0.f;                    // zero accumulator (saves a dispatch)
    }
}

// ---------------- DPP helpers ----------------
__device__ __forceinline__ float dpp_wshr1(float x) {   // lane n <- lane n-1, lane0 <- 0
    return __int_as_float(__builtin_amdgcn_update_dpp(
        0, __float_as_int(x), 0x138, 0xF, 0xF, true));
}
__device__ __forceinline__ int dpp_wshr1_i(int x) {
    return __builtin_amdgcn_update_dpp(0, x, 0x138, 0xF, 0xF, true);
}

// ---------------- DP core ----------------
// R[3] = 3 pair-packed dwordx4: R[p] = {r2p[s0], r2p[s1], r2p+1[s0], r2p+1[s1]}
__device__ __forceinline__ void run6p(const f4 (&R)[3], const float (&pv)[6],
                                      float& a0, float& a1, float& a2, float& a3,
                                      float& aX, float msk1, float msk3, float f) {
#pragma unroll
    for (int u = 0; u < 6; ++u) {
        const float l0 = R[u >> 1][(u & 1) * 2];
        const float l1 = R[u >> 1][(u & 1) * 2 + 1];
        const float pb = pv[u];
        const float u3 = dpp_wshr1(a3) * f;              // old alpha[4i-1], rescaled
        const float n0 = (a0 + u3) * pb;                 // blank 4i
        const float n1 = fmaf(msk1, u3, a1 + a0) * l0;   // label s=2i
        const float n2 = (a2 + a1) * pb;                 // blank 4i+2
        const float n3 = fmaf(msk3, a1, a3 + a2) * l1;   // label s=2i+1
        const float nX = (aX + a3) * pb;                 // cell 256 (lane 63 only valid)
        a0 = n0; a1 = n1; a2 = n2; a3 = n3; aX = nX;
    }
}

__device__ __forceinline__ void renorm(float& a0, float& a1, float& a2,
                                       float& a3, float& aX, int& Sc, float& f) {
    const float m = fmaxf(fmaxf(fmaxf(a0, a1), fmaxf(a2, a3)), aX);
    const bool active = (m > 0.f);
    const int E = active ? (((__float_as_int(m) >> 23) & 0xFF) - 126) : 0;
    const float s = __int_as_float((127 - E) << 23);   // exact 2^-E
    a0 *= s; a1 *= s; a2 *= s; a3 *= s; aX *= s;
    Sc += E;
#pragma unroll
    for (int k = 0; k < 4; ++k) {
        const int scl = dpp_wshr1_i(Sc);
        Sc = active ? Sc : scl;
    }
    int d = dpp_wshr1_i(Sc) - Sc;
    d = min(126, max(-126, d));
    f = __int_as_float((d + 127) << 23);               // exact 2^d
}

// ---------------- DMA ring macros ----------------
// Stage chunk KK (pairs 1+3KK..3+3KK, 3 KB) into ring slot SLOT: 3 x 1 KB
// LDS-DMA. Global src is per-lane (base + 16B*lane); LDS dest is wave-
// uniform base (HW adds lane*16). stok chains addresses after last wait.
#define STAGE(SLOT, KK) do {                                                        \
    const float* _g = lab_base + (size_t)(1 + 3 * (size_t)(KK)) * 256 + 4 * lane + stok; \
    lds_float* _l = rp3 + (SLOT) * 768;                                             \
    __builtin_amdgcn_global_load_lds((gconst_void*)(_g),       (lds_void*)(_l),       16, 0, 0); \
    __builtin_amdgcn_global_load_lds((gconst_void*)(_g + 256), (lds_void*)(_l + 256), 16, 0, 0); \
    __builtin_amdgcn_global_load_lds((gconst_void*)(_g + 512), (lds_void*)(_l + 512), 16, 0, 0); \
} while (0)

// 39 DMA ops outstanding -> wait to 36: oldest chunk's 3 landed in LDS.
// Ties stok (following STAGE stays after) and the next bank's regs (the
// following CREAD writing them stays after).
#define VWAIT(NB)                                                                   \
    asm volatile("s_waitcnt vmcnt(36)"                                              \
                 : "+v"(stok), "+v"(NB[0]), "+v"(NB[1]), "+v"(NB[2]))

#define CREAD(BK, SLOT) do {                                                        \
    const unsigned _a = rbase + (unsigned)(SLOT) * 3072u + 16u * lane;              \
    asm volatile("ds_read_b128 %0, %1"             : "=v"(BK[0]) : "v"(_a));        \
    asm volatile("ds_read_b128 %0, %1 offset:1024" : "=v"(BK[1]) : "v"(_a));        \
    asm volatile("ds_read_b128 %0, %1 offset:2048" : "=v"(BK[2]) : "v"(_a));        \
} while (0)

// Current bank's 3 reads are older than everything issued this section ->
// lgkmcnt(3) always drains them (conservative-safe vs compiler DS ops).
#define CWAIT(BK)                                                                   \
    asm volatile("s_waitcnt lgkmcnt(3)"                                             \
                 : "+v"(BK[0]), "+v"(BK[1]), "+v"(BK[2]))

// One 6-row section consuming bank CUR (chunk c), prefetching chunk c+1
// into bank NXT, staging chunk c+13 into the slot vacated by chunk c-1.
#define SEC_BODY(CUR, NXT) {                                                        \
    STAGE((c + 13) % 14, min(c + 13, NCm1));                                        \
    VWAIT(NXT);                                                                     \
    CREAD(NXT, (c + 1) % 14);                                                       \
    CWAIT(CUR);                                                                     \
    const int toff = 2 + 6 * c;                                                     \
    float pv[6];                                                                    \
    pv[0] = pb_lds[toff];     pv[1] = pb_lds[toff + 1];                             \
    pv[2] = pb_lds[toff + 2]; pv[3] = pb_lds[toff + 3];                             \
    pv[4] = pb_lds[toff + 4]; pv[5] = pb_lds[toff + 5];                             \
    run6p(CUR, pv, a0, a1, a2, a3, aX, msk1, msk3, f);                              \
    renorm(a0, a1, a2, a3, aX, Sc, f);                                              \
}

// ---------------- phase 2: the DP ----------------
__global__ __launch_bounds__(64) void ctc_dp4(
        const float* __restrict__ lab2, const float* __restrict__ pbuf,
        const int* __restrict__ targets, const int* __restrict__ in_len,
        const int* __restrict__ tg_len, float* __restrict__ out) {
    __shared__ float ring[14][768];          // 42 KB: 14 slots x 3 KB
    __shared__ float pb_lds[2048];           // 8 KB blank-prob row
    const int b = blockIdx.x;
    const int lane = threadIdx.x;            // 0..63, owns cells 4i..4i+3
    const int Tb = in_len[b];
    const int Sb = tg_len[b];
    const float* lab_base = lab2 + (size_t)b * 1000 * 256;   // pair-packed
    const float* pb_base  = pbuf + (size_t)b * CT;

    lds_float* rp3 = (lds_float*)&ring[0][0];
    const unsigned rbase = (unsigned)(uintptr_t)rp3;

    const int tg0 = targets[b * CS + 2 * lane];
    const int tg1 = targets[b * CS + 2 * lane + 1];
    const int tgm = dpp_wshr1_i(tg1);        // targets[2i-1] (lane0: 0)
    const float msk1 = (tg0 != tgm) ? 1.f : 0.f;
    const float msk3 = (tg1 != tg0) ? 1.f : 0.f;

    // stage pb row to LDS: 8 x 256-float strips (last overlapped, in-bounds)
#pragma unroll
    for (int k = 0; k < 8; ++k) {
        const int start = (k * 256 + 256 <= CT) ? k * 256 : CT - 256;
        ((f4*)(pb_lds + start))[lane] = ((const f4*)(pb_base + start))[lane];
    }

    // t=0 init: alpha[0]=p_blank, alpha[1]=p(label 0)
    float a0 = 0.f, a1 = 0.f, a2 = 0.f, a3 = 0.f, aX = 0.f;
    {
        const float pb0 = pb_base[0];
        const float pl0 = lab_base[0];       // pair0 float[0] (lane0) = row0, state 1
        if (lane == 0) { a0 = pb0; a1 = pl0; }
    }
    int Sc = 0;
    float f = 1.f;
    renorm(a0, a1, a2, a3, aX, Sc, f);

    // t=1 scalar pre-step (odd half of pair 0) so 6-row chunks start at t=2
    if (Tb > 1) {
        const float2 lb = *(const float2*)(lab_base + 4 * lane + 2);
        const float pb = pb_base[1];
        const float u3 = dpp_wshr1(a3) * f;
        const float n0 = (a0 + u3) * pb;
        const float n1 = fmaf(msk1, u3, a1 + a0) * lb.x;
        const float n2 = (a2 + a1) * pb;
        const float n3 = fmaf(msk3, a1, a3 + a2) * lb.y;
        const float nX = (aX + a3) * pb;
        a0 = n0; a1 = n1; a2 = n2; a3 = n3; aX = nX;
        renorm(a0, a1, a2, a3, aX, Sc, f);
    }

    const int NC = (Tb >= 2) ? (Tb - 2) / 6 : 0;   // 6-row chunks from t=2
    const int NCm1 = NC - 1;
    int stok = 0;                            // ordering token (always 0)

    f4 bA[3] = {0}, bB[3] = {0};             // consumer banks (24 VGPR)

    if (NC >= 1) {
        // clean counter baseline: every earlier load (pb staging, init) drained
        asm volatile("s_waitcnt vmcnt(0) lgkmcnt(0)" : "+v"(stok));
        // prologue: stage chunks 0..12 (39 DMA ops)
        STAGE(0, 0);                STAGE(1, min(1, NCm1));
        STAGE(2, min(2, NCm1));     STAGE(3, min(3, NCm1));
        STAGE(4, min(4, NCm1));     STAGE(5, min(5, NCm1));
        STAGE(6, min(6, NCm1));     STAGE(7, min(7, NCm1));
        STAGE(8, min(8, NCm1));     STAGE(9, min(9, NCm1));
        STAGE(10, min(10, NCm1));   STAGE(11, min(11, NCm1));
        STAGE(12, min(12, NCm1));
        // chunk 0 landed: 39 outstanding -> wait to 36
        asm volatile("s_waitcnt vmcnt(36)"
                     : "+v"(stok), "+v"(bA[0]), "+v"(bA[1]), "+v"(bA[2]));
        CREAD(bA, 0);
        int c = 0;
        while (true) {
            SEC_BODY(bA, bB)
            if (++c >= NC) break;
            SEC_BODY(bB, bA)
            if (++c >= NC) break;
        }
        // full drain; keep banks alive past the drain so late completions
        // cannot clobber reallocated registers.
        asm volatile("s_waitcnt vmcnt(0) lgkmcnt(0)" : "+v"(stok));
        asm volatile("" ::
            "v"(bA[0]), "v"(bA[1]), "v"(bA[2]),
            "v"(bB[0]), "v"(bB[1]), "v"(bB[2]));
    }

    // tail: t = 2+6*NC .. Tb-1 (<=5 steps); compiler-managed loads, ring drained
    for (int t = 2 + 6 * NC; t < Tb; ++t) {
        const float2 lb = *(const float2*)(lab_base
                              + (size_t)(t >> 1) * 256 + 4 * lane + 2 * (t & 1));
        const float pb = pb_lds[t];
        const float u3 = dpp_wshr1(a3) * f;
        const float n0 = (a0 + u3) * pb;
        const float n1 = fmaf(msk1, u3, a1 + a0) * lb.x;
        const float n2 = (a2 + a1) * pb;
        const float n3 = fmaf(msk3, a1, a3 + a2) * lb.y;
        const float nX = (aX + a3) * pb;
        a0 = n0; a1 = n1; a2 = n2; a3 = n3; aX = nX;
    }

    // final: ll = log(alpha[2*Sb] + alpha[2*Sb-1]); per-lane scales -> LSE
    const int idx1 = 2 * Sb;
    const int idx2 = (idx1 - 1 > 0) ? (idx1 - 1) : 0;
    const int b4 = 4 * lane;
    float cres = 0.f;
    if (b4 + 0 == idx1 || b4 + 0 == idx2) cres += a0;
    if (b4 + 1 == idx1 || b4 + 1 == idx2) cres += a1;
    if (b4 + 2 == idx1 || b4 + 2 == idx2) cres += a2;
    if (b4 + 3 == idx1 || b4 + 3 == idx2) cres += a3;
    if (lane == 63 && (idx1 == 256 || idx2 == 256)) cres += aX;

    float l2 = (cres > 0.f) ? (log2f(cres) + (float)Sc) : -1e30f;
    float M = l2;
#pragma unroll
    for (int m = 1; m < 64; m <<= 1) M = fmaxf(M, __shfl_xor(M, m, 64));
    float e = (cres > 0.f) ? exp2f(l2 - M) : 0.f;
#pragma unroll
    for (int m = 1; m < 64; m <<= 1) e += __shfl_xor(e, m, 64);
    if (lane == 0) {
        const float ll = (M + log2f(e)) * LN2_F;
        atomicAdd(out, -ll);
    }
}

extern "C" void kernel_launch(void* const* d_in, const int* in_sizes, int n_in,
                              void* d_out, int out_size, void* d_ws, size_t ws_size,
                              hipStream_t stream) {
    (void)in_sizes; (void)n_in; (void)out_size; (void)ws_size;
    const float* lp      = (const float*)d_in[0];
    const int*   targets = (const int*)d_in[1];
    const int*   in_len  = (const int*)d_in[2];
    const int*   tg_len  = (const int*)d_in[3];
    float* out   = (float*)d_out;
    float* lab2  = (float*)d_ws;                             // 32.77 MB pair-packed
    float* pbuf  = lab2 + (size_t)CB * 1000 * 256;           // +256 KB

    ctc_gather2<<<dim3(CB * (CT / 2)), dim3(256), 0, stream>>>(lp, targets, lab2, pbuf, out);
    ctc_dp4<<<dim3(CB), dim3(64), 0, stream>>>(lab2, pbuf, targets, in_len, tg_len, out);
}